// Round 5
// baseline (595.552 us; speedup 1.0000x reference)
//
#include <hip/hip_runtime.h>
#include <hip/hip_bf16.h>

// Reference: T=8192, D=1024 (input unused numerically), E=16, C=ceil(T/E)=512.
// Outputs concatenated flat as f32: [0]=l_aux(=0), [1 .. T*E*C]=combine1_sec,
// [1+T*E*C .. 1+2*T*E*C)=dispatch_mask (bool as 0.0/1.0).

#define T_TOKENS 8192
#define NUM_EXPERTS 16
#define CAPACITY 512
#define TEC ((size_t)T_TOKENS * NUM_EXPERTS * CAPACITY)  // 67,108,864

// One block, 1024 threads = 16 waves. Wave w owns expert w.
// Ballot+popcount segmented scan over 8192 tokens (128 chunks of 64),
// scattering 1.0f for kept tokens (pos < CAPACITY).
__global__ __launch_bounds__(1024)
void DomainGate_68908455297139_kernel(const int* __restrict__ domain_ids,
                                      const void* __restrict__ mask_raw,
                                      float* __restrict__ out) {
    __shared__ int s_packed;
    if (threadIdx.x == 0) s_packed = 0;
    __syncthreads();

    // Layout detection: if mask were uint8-packed bools, the first 2048 i32
    // words (exactly the 8192-byte buffer) would contain values >1 with
    // overwhelming probability (~10% true density). If it's int32 bools,
    // every word is 0 or 1.
    const int* mw = (const int*)mask_raw;
    int bad = 0;
    for (int i = threadIdx.x; i < 2048; i += 1024) {
        if ((unsigned)mw[i] > 1u) bad = 1;
    }
    if (bad) s_packed = 1;  // benign race: all writers store 1
    __syncthreads();
    const bool packed = (s_packed != 0);
    const unsigned char* mb = (const unsigned char*)mask_raw;

    const int wave = threadIdx.x >> 6;   // expert this wave owns (0..15)
    const int lane = threadIdx.x & 63;

    int running = 0;  // non-masked tokens of this expert seen so far
    const unsigned long long lane_lt = (lane == 0) ? 0ull : ((1ull << lane) - 1ull);

    for (int c = 0; c < T_TOKENS / 64; ++c) {
        const int t = c * 64 + lane;
        const int e = domain_ids[t];
        const bool is_pad = packed ? (mb[t] != 0) : (mw[t] != 0);
        const bool match = (e == wave) && !is_pad;
        const unsigned long long b = __ballot(match);
        if (match) {
            const int pos = running + __popcll(b & lane_lt);
            if (pos < CAPACITY) {
                const size_t idx = 1ull + ((size_t)t * NUM_EXPERTS + wave) * CAPACITY + (size_t)pos;
                out[idx] = 1.0f;        // combine1_sec[t, e, pos] = 1.0
                out[idx + TEC] = 1.0f;  // dispatch_mask[t, e, pos] = true
            }
        }
        running += __popcll(b);
    }
}

extern "C" void kernel_launch(void* const* d_in, const int* in_sizes, int n_in,
                              void* d_out, int out_size, void* d_ws, size_t ws_size,
                              hipStream_t stream) {
    (void)in_sizes; (void)n_in; (void)d_ws; (void)ws_size;
    const int* domain_ids = (const int*)d_in[1];
    const void* mask_raw = d_in[2];
    float* out = (float*)d_out;

    // Zero entire output (l_aux + combine + dispatch). Harness re-poisons
    // with 0xAA before every timed call, so this must run every launch.
    hipMemsetAsync(out, 0, (size_t)out_size * sizeof(float), stream);

    DomainGate_68908455297139_kernel<<<1, 1024, 0, stream>>>(domain_ids, mask_raw, out);
}

// Round 6
// 566.993 us; speedup vs baseline: 1.0504x; 1.0504x over previous
//
#include <hip/hip_runtime.h>
#include <hip/hip_bf16.h>

// Reference: T=8192, E=16, C=512. Outputs flat f32:
// [0]=l_aux(0), [1..TEC]=combine, [1+TEC..1+2*TEC)=dispatch (same 0/1 pattern).
// Strategy: prep kernel computes onepos[e][t] (slot index or -1) into d_ws;
// fill kernel writes the whole 537MB output in one full-BW pass, deriving
// each element from onepos. No separate memset, no scattered stores.

#define T_TOKENS 8192
#define NUM_EXPERTS 16
#define CAPACITY 512
#define TEC (67108864ull)                    // T*E*C
#define TOTAL (134217729ull)                 // 1 + 2*TEC

// ---- prep: single block, 16 waves (wave w = expert w), 4 tokens/lane/iter ----
__global__ __launch_bounds__(1024)
void DomainGate_prep(const int* __restrict__ domain_ids,
                     const void* __restrict__ mask_raw,
                     int* __restrict__ rowinfo /* [E][T] */) {
    __shared__ int s_packed;
    if (threadIdx.x == 0) s_packed = 0;
    __syncthreads();

    // Mask layout detection (int32 bools vs uint8 bools). uint8 layout would
    // put multi-byte values in the first 2048 words (8KB, safe both ways).
    const int* mw = (const int*)mask_raw;
    int bad = 0;
    for (int i = threadIdx.x; i < 2048; i += 1024)
        if ((unsigned)mw[i] > 1u) bad = 1;
    if (bad) s_packed = 1;
    __syncthreads();
    const bool packed = (s_packed != 0);
    const unsigned char* mb = (const unsigned char*)mask_raw;

    const int wave = threadIdx.x >> 6;   // expert
    const int lane = threadIdx.x & 63;
    const unsigned long long lane_lt = (lane == 0) ? 0ull : ((1ull << lane) - 1ull);

    int running = 0;  // matches of this expert seen so far (pre-capacity)
    for (int c = 0; c < T_TOKENS / 256; ++c) {   // 32 iters, 256 tokens/wave/iter
        const int t0 = c * 256 + lane * 4;       // 4 consecutive tokens per lane
        const int4 e4 = *(const int4*)&domain_ids[t0];

        int p0, p1, p2, p3;
        if (packed) {
            p0 = mb[t0 + 0]; p1 = mb[t0 + 1]; p2 = mb[t0 + 2]; p3 = mb[t0 + 3];
        } else {
            const int4 m4 = *(const int4*)&mw[t0];
            p0 = m4.x; p1 = m4.y; p2 = m4.z; p3 = m4.w;
        }
        const int b0 = (e4.x == wave) && !p0;
        const int b1 = (e4.y == wave) && !p1;
        const int b2 = (e4.z == wave) && !p2;
        const int b3 = (e4.w == wave) && !p3;

        const unsigned long long B0 = __ballot(b0);
        const unsigned long long B1 = __ballot(b1);
        const unsigned long long B2 = __ballot(b2);
        const unsigned long long B3 = __ballot(b3);

        // rank of token (lane, j): matches in lanes<lane (any j) + own j'<j
        const int before = __popcll(B0 & lane_lt) + __popcll(B1 & lane_lt) +
                           __popcll(B2 & lane_lt) + __popcll(B3 & lane_lt);
        const int r0 = running + before;
        const int r1 = r0 + b0;
        const int r2 = r1 + b1;
        const int r3 = r2 + b2;

        int4 o;
        o.x = (b0 && r0 < CAPACITY) ? r0 : -1;
        o.y = (b1 && r1 < CAPACITY) ? r1 : -1;
        o.z = (b2 && r2 < CAPACITY) ? r2 : -1;
        o.w = (b3 && r3 < CAPACITY) ? r3 : -1;
        *(int4*)&rowinfo[wave * T_TOKENS + t0] = o;   // e-major, coalesced

        running += __popcll(B0) + __popcll(B1) + __popcll(B2) + __popcll(B3);
    }
}

// ---- fill: one full-BW pass over all TOTAL floats, float4 per thread ----
__global__ __launch_bounds__(256)
void DomainGate_fill(const int* __restrict__ rowinfo, float* __restrict__ out) {
    const size_t ngroups = TOTAL >> 2;               // 33554432 aligned float4 groups
    const size_t stride = (size_t)gridDim.x * blockDim.x;
    size_t g = (size_t)blockIdx.x * blockDim.x + threadIdx.x;

    if (g == 0) {
        // tail element f = 4*ngroups = TOTAL-1 (last dispatch element)
        const size_t r = TOTAL - 2 - TEC;
        const int row = (int)(r >> 9), c = (int)(r & 511);
        const int op = rowinfo[((row & 15) << 13) | (row >> 4)];
        out[TOTAL - 1] = (c == op) ? 1.0f : 0.0f;
    }

    for (; g < ngroups; g += stride) {
        float vals[4];
        #pragma unroll
        for (int j = 0; j < 4; ++j) {
            const size_t f = 4 * g + (size_t)j;
            float v = 0.0f;
            if (f != 0) {                            // f==0 is l_aux = 0
                size_t r = f - 1;
                if (r >= TEC) r -= TEC;              // dispatch mirrors combine
                const int row = (int)(r >> 9), c = (int)(r & 511);
                const int op = rowinfo[((row & 15) << 13) | (row >> 4)];
                v = (c == op) ? 1.0f : 0.0f;
            }
            vals[j] = v;
        }
        *(float4*)&out[4 * g] = make_float4(vals[0], vals[1], vals[2], vals[3]);
    }
}

extern "C" void kernel_launch(void* const* d_in, const int* in_sizes, int n_in,
                              void* d_out, int out_size, void* d_ws, size_t ws_size,
                              hipStream_t stream) {
    (void)in_sizes; (void)n_in; (void)out_size; (void)ws_size;
    const int* domain_ids = (const int*)d_in[1];
    const void* mask_raw = d_in[2];
    float* out = (float*)d_out;
    int* rowinfo = (int*)d_ws;   // 16*8192 ints = 512 KB scratch

    DomainGate_prep<<<1, 1024, 0, stream>>>(domain_ids, mask_raw, rowinfo);
    DomainGate_fill<<<2048, 256, 0, stream>>>(rowinfo, out);
}

// Round 7
// 557.676 us; speedup vs baseline: 1.0679x; 1.0167x over previous
//
#include <hip/hip_runtime.h>
#include <hip/hip_bf16.h>

// Reference: T=8192, E=16, C=512. Outputs flat f32:
// [0]=l_aux(0), [1..TEC]=combine, [1+TEC..1+2*TEC)=dispatch (same 0/1 pattern).
//
// Strategy: hipMemsetAsync zeros the whole 537 MB output at runtime-fill BW
// (measured 6.3 TB/s), then a 16-block scatter kernel (block e = expert e,
// 64 lanes, int4-vectorized ballot scan) writes the ~920 ones directly.
//
// Mask dtype: r1 (read as uint8) failed with +-1.0 position shifts; r5 (int32
// path chosen by runtime detection) passed => bool mask is uploaded as int32.

#define T_TOKENS 8192
#define NUM_EXPERTS 16
#define CAPACITY 512
#define TEC (67108864ull)     // T*E*C
#define TOTAL (134217729ull)  // 1 + 2*TEC

__global__ __launch_bounds__(64)
void DomainGate_scatter(const int* __restrict__ domain_ids,
                        const int* __restrict__ mask_i32,
                        float* __restrict__ out) {
    const int e = blockIdx.x;          // expert this block owns
    const int lane = threadIdx.x;      // 0..63
    const unsigned long long lane_lt = (lane == 0) ? 0ull : ((1ull << lane) - 1ull);

    int running = 0;  // non-masked tokens of expert e seen so far
    for (int c = 0; c < T_TOKENS / 256; ++c) {   // 32 iters, 256 tokens/iter
        const int t0 = c * 256 + lane * 4;       // 4 consecutive tokens per lane
        const int4 e4 = *(const int4*)&domain_ids[t0];
        const int4 m4 = *(const int4*)&mask_i32[t0];

        const int b0 = (e4.x == e) && !m4.x;
        const int b1 = (e4.y == e) && !m4.y;
        const int b2 = (e4.z == e) && !m4.z;
        const int b3 = (e4.w == e) && !m4.w;

        const unsigned long long B0 = __ballot(b0);
        const unsigned long long B1 = __ballot(b1);
        const unsigned long long B2 = __ballot(b2);
        const unsigned long long B3 = __ballot(b3);

        // rank of token (lane,j) among expert-e tokens in this chunk:
        // all matches in lanes<lane plus own earlier j's.
        const int before = __popcll(B0 & lane_lt) + __popcll(B1 & lane_lt) +
                           __popcll(B2 & lane_lt) + __popcll(B3 & lane_lt);
        const int r0 = running + before;
        const int r1 = r0 + b0;
        const int r2 = r1 + b1;
        const int r3 = r2 + b2;

        if (b0 && r0 < CAPACITY) {
            const size_t idx = 1ull + ((size_t)(t0 + 0) * NUM_EXPERTS + e) * CAPACITY + (size_t)r0;
            out[idx] = 1.0f; out[idx + TEC] = 1.0f;
        }
        if (b1 && r1 < CAPACITY) {
            const size_t idx = 1ull + ((size_t)(t0 + 1) * NUM_EXPERTS + e) * CAPACITY + (size_t)r1;
            out[idx] = 1.0f; out[idx + TEC] = 1.0f;
        }
        if (b2 && r2 < CAPACITY) {
            const size_t idx = 1ull + ((size_t)(t0 + 2) * NUM_EXPERTS + e) * CAPACITY + (size_t)r2;
            out[idx] = 1.0f; out[idx + TEC] = 1.0f;
        }
        if (b3 && r3 < CAPACITY) {
            const size_t idx = 1ull + ((size_t)(t0 + 3) * NUM_EXPERTS + e) * CAPACITY + (size_t)r3;
            out[idx] = 1.0f; out[idx + TEC] = 1.0f;
        }

        running += __popcll(B0) + __popcll(B1) + __popcll(B2) + __popcll(B3);
    }
}

extern "C" void kernel_launch(void* const* d_in, const int* in_sizes, int n_in,
                              void* d_out, int out_size, void* d_ws, size_t ws_size,
                              hipStream_t stream) {
    (void)in_sizes; (void)n_in; (void)d_ws; (void)ws_size;
    const int* domain_ids = (const int*)d_in[1];
    const int* mask_i32 = (const int*)d_in[2];
    float* out = (float*)d_out;

    // Zero entire output (l_aux + combine + dispatch) at runtime-fill BW.
    hipMemsetAsync(out, 0, (size_t)out_size * sizeof(float), stream);

    // Scatter the ~920 ones (two mirrored halves), one expert per block.
    DomainGate_scatter<<<NUM_EXPERTS, 64, 0, stream>>>(domain_ids, mask_i32, out);
}

// Round 8
// 556.282 us; speedup vs baseline: 1.0706x; 1.0025x over previous
//
#include <hip/hip_runtime.h>
#include <hip/hip_bf16.h>

// Reference: T=8192, E=16, C=512. Outputs flat f32:
// [0]=l_aux(0), [1..TEC]=combine, [1+TEC..1+2*TEC)=dispatch (same 0/1 pattern).
//
// Strategy (r8): prep kernel computes rowinfo[e][t] = slot index or -1 (ballot
// scan, validated r6/r7; mask is int32 bools, proven r7). Then ONE fused
// kernel: each of 2048 blocks zero-fills its contiguous 256KB chunk with pure
// float4 stores (no per-element math -> fill-BW), syncs, and writes the <=260
// candidate ones whose flat index falls inside its own chunk.

#define T_TOKENS 8192
#define NUM_EXPERTS 16
#define CAPACITY 512
#define TEC (67108864ll)      // T*E*C
#define TOTAL (134217729ll)   // 1 + 2*TEC
#define NROWS (131072)        // T*E rows of length C
#define FPB (65536ll)         // floats per block (2048 blocks)

// ---- prep: 1 block, 16 waves (wave w = expert w), int4-vectorized ----
__global__ __launch_bounds__(1024)
void DomainGate_prep(const int* __restrict__ domain_ids,
                     const int* __restrict__ mask_i32,
                     int* __restrict__ rowinfo /* [E][T] */) {
    const int wave = threadIdx.x >> 6;   // expert
    const int lane = threadIdx.x & 63;
    const unsigned long long lane_lt = (lane == 0) ? 0ull : ((1ull << lane) - 1ull);

    int running = 0;
    for (int c = 0; c < T_TOKENS / 256; ++c) {   // 32 iters, 256 tokens/iter
        const int t0 = c * 256 + lane * 4;
        const int4 e4 = *(const int4*)&domain_ids[t0];
        const int4 m4 = *(const int4*)&mask_i32[t0];

        const int b0 = (e4.x == wave) && !m4.x;
        const int b1 = (e4.y == wave) && !m4.y;
        const int b2 = (e4.z == wave) && !m4.z;
        const int b3 = (e4.w == wave) && !m4.w;

        const unsigned long long B0 = __ballot(b0);
        const unsigned long long B1 = __ballot(b1);
        const unsigned long long B2 = __ballot(b2);
        const unsigned long long B3 = __ballot(b3);

        const int before = __popcll(B0 & lane_lt) + __popcll(B1 & lane_lt) +
                           __popcll(B2 & lane_lt) + __popcll(B3 & lane_lt);
        const int r0 = running + before;
        const int r1 = r0 + b0;
        const int r2 = r1 + b1;
        const int r3 = r2 + b2;

        int4 o;
        o.x = (b0 && r0 < CAPACITY) ? r0 : -1;
        o.y = (b1 && r1 < CAPACITY) ? r1 : -1;
        o.z = (b2 && r2 < CAPACITY) ? r2 : -1;
        o.w = (b3 && r3 < CAPACITY) ? r3 : -1;
        *(int4*)&rowinfo[wave * T_TOKENS + t0] = o;   // e-major

        running += __popcll(B0) + __popcll(B1) + __popcll(B2) + __popcll(B3);
    }
}

// ---- fused fill+ones: 2048 blocks x 256 threads, 65536 floats/block ----
__global__ __launch_bounds__(256)
void DomainGate_fill(const int* __restrict__ rowinfo, float* __restrict__ out) {
    const long long f0 = (long long)blockIdx.x * FPB;
    long long f1 = f0 + FPB;
    if (blockIdx.x == gridDim.x - 1) f1 = TOTAL;   // +1 tail element

    // Phase 1: pure float4 zero stores over [f0, f0+FPB) — fill-BW.
    {
        float4* p = (float4*)(out + f0);
        const float4 z = make_float4(0.f, 0.f, 0.f, 0.f);
        #pragma unroll 8
        for (int i = 0; i < (int)(FPB / 4 / 256); ++i)    // 64 stores/thread
            p[i * 256 + threadIdx.x] = z;
        if (f1 != f0 + FPB && threadIdx.x == 0)
            out[TOTAL - 1] = 0.0f;                        // tail element
    }
    __syncthreads();

    // Phase 2: write the ones whose index falls in [f0, f1).
    // Row r (0..NROWS-1) of half h occupies [base_h + 512r, base_h + 512r + 512).
    #pragma unroll
    for (int h = 0; h < 2; ++h) {
        const long long base = 1ll + (long long)h * TEC;
        long long lo = (f0 - base) >> 9;                  // floor; may be <0
        if (lo < 0) lo = 0;
        long long hi = (f1 - 1 - base) >> 9;
        if (hi >= NROWS) hi = NROWS - 1;
        // at most ~130 rows; one thread per row
        const long long r = lo + (long long)threadIdx.x;
        if (r <= hi) {
            const int row = (int)r;
            const int op = rowinfo[((row & 15) << 13) | (row >> 4)];  // [e][t]
            if (op >= 0) {
                const long long idx = base + ((long long)row << 9) + op;
                if (idx >= f0 && idx < f1) out[idx] = 1.0f;
            }
        }
    }
}

extern "C" void kernel_launch(void* const* d_in, const int* in_sizes, int n_in,
                              void* d_out, int out_size, void* d_ws, size_t ws_size,
                              hipStream_t stream) {
    (void)in_sizes; (void)n_in; (void)out_size; (void)ws_size;
    const int* domain_ids = (const int*)d_in[1];
    const int* mask_i32 = (const int*)d_in[2];
    float* out = (float*)d_out;
    int* rowinfo = (int*)d_ws;   // 16*8192 ints = 512 KB scratch

    DomainGate_prep<<<1, 1024, 0, stream>>>(domain_ids, mask_i32, rowinfo);
    DomainGate_fill<<<2048, 256, 0, stream>>>(rowinfo, out);
}